// Round 5
// baseline (284.491 us; speedup 1.0000x reference)
//
#include <hip/hip_runtime.h>
#include <hip/hip_bf16.h>
#include <math.h>

// CRF loss on MI355X — de-fused, latency-optimized.
//   k_prep:    W fp32->bf16 (pad 52->64), expT = exp(Tpad) bf16, zero gold
//   k_emit:    emit GEMM (M=16/wave, A 4-deep + B 2-deep prefetch) -> bf16 emit
//   k_scan:    per-wave 16-step transfer-matrix product; E=exp2(emit*log2e-7)
//              precomputed in LDS (no transcendentals in the step chain);
//              gold partial from E via log2; dump bf16 chunks (coalesced layout)
//   k_combine: 32 sequential 64x64 bf16 matvecs per batch + last-tag + mean
//
// Scan math: P <- diag(exp(emit_t)*2^-(7+r)) * exp(Tpad) * P; exact pow-2
// rescale at t==7; integer exponent accumulated in eacc (7/step baseline).
// Padding: Tpad[i][j>=52]=NEG (exp->0), Tpad[i>=52][j<52]=0 (finite pad rows,
// excluded at the end by exp(TSTOP[j>=52])=0). All k_scan LDS is wave-private
// and accessed in program order -> NO __syncthreads in k_scan.

#define NEGV   (-100000000.0f)
#define BB     64
#define TT     512
#define FF     1024
#define HH     52
#define HP     64
#define S_START 50
#define S_STOP  51
#define NCH    32            // chunks per batch
#define CLEN   (TT / NCH)    // 16 steps per chunk

typedef __bf16 bf16x8 __attribute__((ext_vector_type(8)));
typedef __bf16 bf16x4 __attribute__((ext_vector_type(4)));
typedef float  f32x4  __attribute__((ext_vector_type(4)));

// ---------------- ws layout (bytes) ----------------
#define WS_CHUNK  0u           // bf16 [2048][8][64][8]  16,777,216
#define WS_EMITB  16777216u    // bf16 [B*T][HP]          4,194,304
#define WS_WBF    20971520u    // bf16 [HP][FF]             131,072
#define WS_EXPT   21102592u    // bf16 [64][64]               8,192
#define WS_GOLD   21110784u    // fp32 [BB]                     256
#define WS_CEXP   21111040u    // fp32 [2048]                 8,192

// ---- W fp32 -> bf16 (pad rows 52..63 = 0); block 0: gold=0 and expT ----
__global__ __launch_bounds__(256) void k_prep(const float* __restrict__ W,
                                              const float* __restrict__ trans,
                                              __bf16* __restrict__ wbf,
                                              __bf16* __restrict__ expT,
                                              float* __restrict__ gold) {
  int n = blockIdx.x;  // 0..63
  if (n == 0) {
    if (threadIdx.x < BB) gold[threadIdx.x] = 0.0f;
    for (int idx = threadIdx.x; idx < 4096; idx += 256) {
      int m = idx >> 6, k = idx & 63;
      float tv = (k >= HH) ? NEGV : ((m >= HH) ? 0.0f : trans[m * HH + k]);
      expT[idx] = (__bf16)__expf(tv);
    }
  }
  for (int k = threadIdx.x; k < FF; k += 256) {
    float v = (n < HH) ? W[n * FF + k] : 0.0f;
    wbf[n * FF + k] = (__bf16)v;
  }
}

// ---- emit GEMM: 512 blocks x 4 waves; M=16/wave, N=64, K=1024 ----
// A (feat fp32) 4-deep register prefetch; B (wbf, L2-hot) 2-deep prefetch.
__global__ __launch_bounds__(256, 2) void k_emit(const float* __restrict__ feat,
                                                 const __bf16* __restrict__ wbf,
                                                 const float* __restrict__ bias,
                                                 __bf16* __restrict__ emitb) {
  const int tid = threadIdx.x;
  const int wv = tid >> 6;
  const int l  = tid & 63;
  const int lm = l & 15;
  const int q  = l >> 4;
  const size_t row0 = (size_t)blockIdx.x * 64 + wv * 16;
  const float* arow = feat + (row0 + lm) * FF + q * 8;

  float bn[4];
#pragma unroll
  for (int nt = 0; nt < 4; ++nt) {
    int n = nt * 16 + lm;
    bn[nt] = (n < HH) ? bias[n] : 0.0f;
  }

  f32x4 apre[4][2];
#pragma unroll
  for (int s = 0; s < 4; ++s)
#pragma unroll
    for (int h = 0; h < 2; ++h)
      apre[s][h] = *(const f32x4*)(arow + s * 32 + h * 4);

  bf16x8 bpre[2][4];
#pragma unroll
  for (int sb = 0; sb < 2; ++sb)
#pragma unroll
    for (int nt = 0; nt < 4; ++nt)
      bpre[sb][nt] = *(const bf16x8*)(wbf + (size_t)(nt * 16 + lm) * FF + sb * 32 + q * 8);

  f32x4 acc[4] = {};

#pragma unroll
  for (int kt = 0; kt < 32; ++kt) {
    const int st = kt & 3, sb = kt & 1;
    bf16x8 af;
#pragma unroll
    for (int j = 0; j < 4; ++j) {
      af[j]     = (__bf16)apre[st][0][j];
      af[4 + j] = (__bf16)apre[st][1][j];
    }
#pragma unroll
    for (int nt = 0; nt < 4; ++nt)
      acc[nt] = __builtin_amdgcn_mfma_f32_16x16x32_bf16(af, bpre[sb][nt], acc[nt], 0, 0, 0);
    if (kt + 4 < 32) {
#pragma unroll
      for (int h = 0; h < 2; ++h)
        apre[st][h] = *(const f32x4*)(arow + (kt + 4) * 32 + h * 4);
    }
    if (kt + 2 < 32) {
#pragma unroll
      for (int nt = 0; nt < 4; ++nt)
        bpre[sb][nt] = *(const bf16x8*)(wbf + (size_t)(nt * 16 + lm) * FF + (kt + 2) * 32 + q * 8);
    }
  }

  // D: row = q*4+rr, col = nt*16+lm  -> emitb[t][state] bf16
#pragma unroll
  for (int nt = 0; nt < 4; ++nt)
#pragma unroll
    for (int rr = 0; rr < 4; ++rr)
      emitb[(row0 + q * 4 + rr) * HP + nt * 16 + lm] = (__bf16)(acc[nt][rr] + bn[nt]);
}

// ---- scan: 512 blocks x 4 waves = 2048 wave-chunks (CLEN=16, no barriers) ----
__global__ __launch_bounds__(256, 2) void k_scan(const __bf16* __restrict__ emitb,
                                                 const __bf16* __restrict__ expT,
                                                 const float* __restrict__ trans,
                                                 const float* __restrict__ masks,
                                                 const int* __restrict__ tags,
                                                 __bf16* __restrict__ chunks,
                                                 float* __restrict__ cexp,
                                                 float* __restrict__ gold) {
  const int tid = threadIdx.x;
  const int wv = tid >> 6;
  const int l  = tid & 63;
  const int lm = l & 15;
  const int q  = l >> 4;
  const int chunk = blockIdx.x * 4 + wv;   // 0..2047
  const int b = chunk >> 5, c = chunk & 31;

  __shared__ __align__(16) __bf16 PTall[4][64 * 72];   // 36,864 B
  __shared__ __align__(16) float  Eall[4][CLEN * 64];  // 16,384 B
  __bf16* pt = PTall[wv];
  float*  E  = Eall[wv];

  const float LOG2E = 1.4426950408889634f;
  const float LN2   = 0.6931471805599453f;

  // ---- load emit tile (2 KB/wave, coalesced) -> E = exp2(e*log2e - 7) ----
  const __bf16* tb = emitb + (size_t)(b * TT + c * CLEN) * HP;
  bf16x8 v0 = *(const bf16x8*)(tb + l * 16);
  bf16x8 v1 = *(const bf16x8*)(tb + l * 16 + 8);
  float ev[16];
#pragma unroll
  for (int j = 0; j < 8; ++j) {
    ev[j]     = __builtin_amdgcn_exp2f(fmaf((float)v0[j], LOG2E, -7.0f));
    ev[8 + j] = __builtin_amdgcn_exp2f(fmaf((float)v1[j], LOG2E, -7.0f));
  }
#pragma unroll
  for (int h = 0; h < 4; ++h) {
    f32x4 e4 = { ev[h * 4], ev[h * 4 + 1], ev[h * 4 + 2], ev[h * 4 + 3] };
    *(f32x4*)&E[l * 16 + h * 4] = e4;
  }

  // ---- constant A = exp(Tpad) ----
  bf16x8 afrag[4][2];
#pragma unroll
  for (int mt = 0; mt < 4; ++mt)
#pragma unroll
    for (int kk = 0; kk < 2; ++kk)
      afrag[mt][kk] = *(const bf16x8*)&expT[(mt * 16 + lm) * 64 + kk * 32 + q * 8];

  // ---- P = I ----
  for (int idx = l; idx < 4096; idx += 64) {
    int n = idx >> 6, mm = idx & 63;
    pt[n * 72 + mm] = (__bf16)((n == mm) ? 1.0f : 0.0f);
  }

  // ---- gold partial (from E via log2; exact round-trip to float precision) ----
  float mreg = (l < CLEN) ? masks[b * TT + c * CLEN + l] : 1.0f;
  int cur = (l < CLEN) ? tags[b * TT + c * CLEN + l] : 0;
  int prev = __shfl_up(cur, 1);
  if (l == 0) prev = (c == 0) ? S_START : tags[b * TT + c * CLEN - 1];
  float gp = 0.0f;
  if (l < CLEN) {
    float e = fmaf(__log2f(E[l * 64 + cur]), LN2, 7.0f * LN2);
    gp = (e + trans[cur * HH + prev]) * mreg;
  }
#pragma unroll
  for (int d = 1; d < 64; d <<= 1) gp += __shfl_xor(gp, d);
  if (l == 0) atomicAdd(&gold[b], gp);

  // ---- 16-step product; chain = LDS read -> MFMA -> mul/cvt -> LDS write ----
  int eacc = 0, rpend = 0;
  float rs = 1.0f;

  for (int t = 0; t < CLEN; ++t) {
    float mcur = __shfl(mreg, t);             // wave-uniform
    if (mcur != 0.0f) {
      eacc += 7 + rpend;
      float s[4][4];
#pragma unroll
      for (int mt = 0; mt < 4; ++mt) {
        f32x4 e4 = *(const f32x4*)&E[t * 64 + mt * 16 + q * 4];  // broadcast reads
#pragma unroll
        for (int rr = 0; rr < 4; ++rr) s[mt][rr] = e4[rr] * rs;
      }

      // ALL reads before ALL writes (in-order LDS per wave)
      bf16x8 bfr[2][4];
#pragma unroll
      for (int kk = 0; kk < 2; ++kk)
#pragma unroll
        for (int nt = 0; nt < 4; ++nt)
          bfr[kk][nt] = *(const bf16x8*)&pt[(nt * 16 + lm) * 72 + kk * 32 + q * 8];

      const bool trk = (t == 7);
      float lmax = 0.0f;
      f32x4 zero = {};
#pragma unroll
      for (int mt = 0; mt < 4; ++mt) {
#pragma unroll
        for (int nt = 0; nt < 4; ++nt) {
          f32x4 a = __builtin_amdgcn_mfma_f32_16x16x32_bf16(afrag[mt][0], bfr[0][nt], zero, 0, 0, 0);
          a = __builtin_amdgcn_mfma_f32_16x16x32_bf16(afrag[mt][1], bfr[1][nt], a, 0, 0, 0);
          bf16x4 w4;
#pragma unroll
          for (int rr = 0; rr < 4; ++rr) {
            float v = a[rr] * s[mt][rr];
            if (trk) lmax = fmaxf(lmax, v);
            w4[rr] = (__bf16)v;
          }
          *(bf16x4*)&pt[(nt * 16 + lm) * 72 + mt * 16 + q * 4] = w4;
        }
      }
      if (trk) {
#pragma unroll
        for (int d = 1; d < 64; d <<= 1) lmax = fmaxf(lmax, __shfl_xor(lmax, d));
        rpend = ilogbf(lmax);                 // exact pow2, applied next step
        rs = __builtin_amdgcn_exp2f(-(float)rpend);
      } else {
        rpend = 0;
        rs = 1.0f;
      }
    }
  }

  // ---- dump: chunks[chunk][jj][lane][e] = P[lane][jj*8+e]; fully coalesced ----
  __bf16* cb = chunks + (size_t)chunk * 4096;
#pragma unroll
  for (int jj = 0; jj < 8; ++jj) {
    bf16x8 w;
#pragma unroll
    for (int e = 0; e < 8; ++e) w[e] = pt[(jj * 8 + e) * 72 + l];
    *(bf16x8*)(cb + jj * 512 + l * 8) = w;
  }
  if (l == 0) cexp[chunk] = (float)eacc;
}

// ---- combine: 64 blocks x 1 wave; 32 bf16 matvecs, double-buffered ----
__global__ __launch_bounds__(64) void k_combine(const __bf16* __restrict__ chunks,
                                                const float* __restrict__ cexp,
                                                const float* __restrict__ trans,
                                                const float* __restrict__ masks,
                                                const int* __restrict__ tags,
                                                const float* __restrict__ gold,
                                                float* __restrict__ out) {
  const int b = blockIdx.x;
  const int l = threadIdx.x;   // 0..63 = state i
  __shared__ float vsh[64];
  float v = (l == S_START) ? 1.0f : 0.0f;
  float esum = 0.0f;
  const float LN2 = 0.6931471805599453f;

  float msum = 0.0f;
  for (int t = l; t < TT; t += 64) msum += masks[b * TT + t];

  bf16x8 mb[2][8];
  {
    const __bf16* base = chunks + (size_t)(b * NCH) * 4096;
#pragma unroll
    for (int jj = 0; jj < 8; ++jj) mb[0][jj] = *(const bf16x8*)(base + jj * 512 + l * 8);
  }

#pragma unroll
  for (int cc = 0; cc < NCH; ++cc) {
    vsh[l] = v;
    __syncthreads();
    if (cc + 1 < NCH) {
      const __bf16* bn = chunks + (size_t)(b * NCH + cc + 1) * 4096;
#pragma unroll
      for (int jj = 0; jj < 8; ++jj) mb[(cc + 1) & 1][jj] = *(const bf16x8*)(bn + jj * 512 + l * 8);
    }
    float u0 = 0.f, u1 = 0.f;
#pragma unroll
    for (int jj = 0; jj < 8; ++jj) {
      bf16x8 m8 = mb[cc & 1][jj];
      const float* vj = &vsh[jj * 8];
#pragma unroll
      for (int e = 0; e < 4; ++e) {
        u0 += (float)m8[e] * vj[e];
        u1 += (float)m8[4 + e] * vj[4 + e];
      }
    }
    float u = u0 + u1;
    esum += cexp[b * NCH + cc] * LN2;
    float mxx = u;
#pragma unroll
    for (int d = 1; d < 64; d <<= 1) mxx = fmaxf(mxx, __shfl_xor(mxx, d));
    if (mxx > 0.0f) {
      int ee = ilogbf(mxx);
      u = ldexpf(u, -ee);
      esum += (float)ee * LN2;
    }
    v = u;
    __syncthreads();
  }

  float ts = (l < HH) ? trans[S_STOP * HH + l] : NEGV;  // exp(NEG)=0 excludes pads
  float contrib = v * __expf(ts);
#pragma unroll
  for (int d = 1; d < 64; d <<= 1) {
    contrib += __shfl_xor(contrib, d);
    msum += __shfl_xor(msum, d);
  }
  if (l == 0) {
    int lp = (int)(msum + 0.5f);
    int lt = (lp == 0) ? S_START : tags[b * TT + lp - 1];
    float goldb = gold[b] + trans[S_STOP * HH + lt];
    float fwd = __logf(contrib) + esum;
    atomicAdd(out, (fwd - goldb) * (1.0f / 64.0f));
  }
}

extern "C" void kernel_launch(void* const* d_in, const int* in_sizes, int n_in,
                              void* d_out, int out_size, void* d_ws, size_t ws_size,
                              hipStream_t stream) {
  (void)in_sizes; (void)n_in; (void)out_size; (void)ws_size;
  const float* feat  = (const float*)d_in[0];
  const float* W     = (const float*)d_in[1];
  const float* bias  = (const float*)d_in[2];
  const float* trans = (const float*)d_in[3];
  const float* masks = (const float*)d_in[4];
  const int*   tags  = (const int*)d_in[5];

  char* ws = (char*)d_ws;
  __bf16* chunks = (__bf16*)(ws + WS_CHUNK);
  __bf16* emitb  = (__bf16*)(ws + WS_EMITB);
  __bf16* wbf    = (__bf16*)(ws + WS_WBF);
  __bf16* expT   = (__bf16*)(ws + WS_EXPT);
  float*  gold   = (float*)(ws + WS_GOLD);
  float*  cexp   = (float*)(ws + WS_CEXP);

  hipMemsetAsync(d_out, 0, sizeof(float), stream);
  k_prep<<<HP, 256, 0, stream>>>(W, trans, wbf, expT, gold);
  k_emit<<<(BB * TT) / 64, 256, 0, stream>>>(feat, wbf, bias, emitb);
  k_scan<<<(BB * NCH) / 4, 256, 0, stream>>>(emitb, expT, trans, masks, tags,
                                             chunks, cexp, gold);
  k_combine<<<BB, 64, 0, stream>>>(chunks, cexp, trans, masks, tags, gold, (float*)d_out);
}